// Round 16
// baseline (1407.667 us; speedup 1.0000x reference)
//
#include <hip/hip_runtime.h>

// Problem constants
#define NB 2
#define DD 192
#define HH 192
#define WW 192
#define HWSZ (HH * WW)
#define C1F 0.0001f
#define C2F 0.0009f

// Tiling: 1-WAVE blocks (64 threads). 8(H) x 16(W) outputs, stream D.
#define TH 8
#define TW 16
#define CHUNK 32
#define TSTEPS (CHUNK + 10)          // 42
#define NCH (DD / CHUNK)             // 6
#define NTH (HH / TH)                // 24
#define NTW (WW / TW)                // 12
#define NBLK (NB * NCH * NTH * NTW)  // 3456

#define SROWS (TH + 10)              // 18 staged/W-blurred rows
#define SCOLS 26                     // staged cols (w0-5 .. w0+20)
#define SP2 28                       // s2 row stride in float2 (even -> f4 aligned)
#define TQ 19                        // t4 row stride in quads
#define NSTG (SROWS * SCOLS)         // 468 stage tasks (8 rounds of 64)
#define NWT (SROWS * (TW / 4))       // 72 W-blur tasks (64 + 8)

// Gaussian weights, WIN=11, sigma=1.5
#define KWLIST { 0.00102838f, 0.00759876f, 0.03600077f, 0.10936071f, 0.21300556f, \
                 0.26601172f, 0.21300556f, 0.10936071f, 0.03600077f, 0.00759876f, 0.00102838f }

// Packed f32 FMA (weights as VGPR broadcast pairs — proven form from R14).
__device__ __forceinline__ void pk_fma(float2& acc, float2 a, float2 k2) {
  asm("v_pk_fma_f32 %0, %1, %2, %0" : "+v"(acc) : "v"(a), "v"(k2));
}

// SSIM from 4 packed stats: mu1, mu2, A=blur((x+y)^2), Bm=blur((x-y)^2).
__device__ __forceinline__ float ssim_val(float mu1, float mu2, float A, float Bm) {
  const float mu1sq = mu1 * mu1, mu2sq = mu2 * mu2, mu12 = mu1 * mu2;
  const float num = (2.f * mu12 + C1F) * (0.5f * (A - Bm) - 2.f * mu12 + C2F);
  const float den = (mu1sq + mu2sq + C1F) * (0.5f * (A + Bm) - mu1sq - mu2sq + C2F);
  return num * __builtin_amdgcn_rcpf(den);
}

__global__ __launch_bounds__(64, 3) void ssim_fused(
    const float* __restrict__ x, const float* __restrict__ y,
    float* __restrict__ partials) {
  const float KW[11] = KWLIST;
  float2 KW2[11];
#pragma unroll
  for (int i = 0; i < 11; ++i) KW2[i] = make_float2(KW[i], KW[i]);

  int bid = blockIdx.x;
  const int tw = bid % NTW; bid /= NTW;
  const int th = bid % NTH; bid /= NTH;
  const int c  = bid % NCH; bid /= NCH;
  const int b  = bid;
  const int h0 = th * TH, w0 = tw * TW, c0 = c * CHUNK;

  __shared__ __align__(16) float2 s2[2][SROWS][SP2];  // staged {x,y}, dbuf
  __shared__ float4 t4[SROWS][TQ];                    // W-blurred 4 fields

  const int lane = threadIdx.x;        // 0..63
  const int cl  = lane & 15;           // own W col
  const int r0  = 2 * (lane >> 4);     // own output rows r0, r0+1 (0,2,4,6)
  // t4 store-rotation inverse: pixel col c lives at (c&~3)|(((c&3)+(c>>2))&3)
  const int clp2 = (cl & ~3) | (((cl & 3) + (cl >> 2)) & 3);

  // ---- hoisted stage-task addressing: 468 scalar tasks, 8 rounds ----
  int  sIdx[8], sOff[8];
  bool sOk[8];
#pragma unroll
  for (int k = 0; k < 8; ++k) {
    const int q = lane + 64 * k;
    const bool act = (q < NSTG);
    const int row = q / SCOLS, col = q % SCOLS;
    const int gh = h0 - 5 + row, gw = w0 - 5 + col;
    sOk[k]  = act && (unsigned)gh < (unsigned)HH && (unsigned)gw < (unsigned)WW;
    sIdx[k] = row * SP2 + col;
    sOff[k] = gh * WW + gw;
  }
  // W-blur tasks: round 1 = all 64 lanes (rows 0..15), round 2 = lanes 0..7
  const int  wr1 = lane >> 2, wg1 = lane & 3;
  const bool w2  = (lane < NWT - 64);          // 8 lanes
  const int  wr2 = 16 + (lane >> 2), wg2 = lane & 3;
  const int  tb1 = wr1 * TQ + 4 * wg1;
  const int  tb2 = wr2 * TQ + 4 * wg2;

  // zero-init both s2 buffers (OOB cols stay zero all kernel)
  {
    const float2 z = make_float2(0.f, 0.f);
    float2* sb = &s2[0][0][0];
    for (int q = lane; q < 2 * SROWS * SP2; q += 64) sb[q] = z;
  }
  __syncthreads();

  const float* xb = x + (size_t)b * DD * HWSZ;
  const float* yb = y + (size_t)b * DD * HWSZ;

  auto do_stage = [&](int g, float2* s2buf) {
    const float* xs = xb + (size_t)g * HWSZ;
    const float* ys = yb + (size_t)g * HWSZ;
    float gx[8], gy[8];
#pragma unroll
    for (int k = 0; k < 8; ++k)
      if (sOk[k]) { gx[k] = xs[sOff[k]]; gy[k] = ys[sOff[k]]; }
#pragma unroll
    for (int k = 0; k < 8; ++k)
      if (sOk[k]) s2buf[sIdx[k]] = make_float2(gx[k], gy[k]);
  };

  auto wtask = [&](const float2* s2buf, int wr, int wg, int tb) {
    const float4* srow4 = (const float4*)(s2buf + wr * SP2);
    float2 a0p = make_float2(0.f, 0.f), a0q = a0p, a1p = a0p, a1q = a0p,
           a2p = a0p, a2q = a0p, a3p = a0p, a3q = a0p;
#pragma unroll
    for (int u2 = 0; u2 < 7; ++u2) {
      const float4 v2 = srow4[2 * wg + u2];   // staged cols 4wg+2u2, +1
#pragma unroll
      for (int h = 0; h < 2; ++h) {
        const int    u  = 2 * u2 + h;
        const float  xx = h ? v2.z : v2.x;
        const float  yy = h ? v2.w : v2.y;
        const float2 xy = make_float2(xx, yy);
        const float  sm = xx + yy, df = xx - yy;
        const float2 sqdq = make_float2(sm * sm, df * df);
        if (u <= 10)           { pk_fma(a0p, xy, KW2[u]);     pk_fma(a0q, sqdq, KW2[u]); }
        if (u >= 1 && u <= 11) { pk_fma(a1p, xy, KW2[u - 1]); pk_fma(a1q, sqdq, KW2[u - 1]); }
        if (u >= 2 && u <= 12) { pk_fma(a2p, xy, KW2[u - 2]); pk_fma(a2q, sqdq, KW2[u - 2]); }
        if (u >= 3)            { pk_fma(a3p, xy, KW2[u - 3]); pk_fma(a3q, sqdq, KW2[u - 3]); }
      }
    }
    float4* tp = &t4[0][0];
    tp[tb + ((0 + wg) & 3)] = make_float4(a0p.x, a0p.y, a0q.x, a0q.y);
    tp[tb + ((1 + wg) & 3)] = make_float4(a1p.x, a1p.y, a1q.x, a1q.y);
    tp[tb + ((2 + wg) & 3)] = make_float4(a2p.x, a2p.y, a2q.x, a2q.y);
    tp[tb + ((3 + wg) & 3)] = make_float4(a3p.x, a3p.y, a3q.x, a3q.y);
  };

  // Ring accumulators: 2 output rows x {mu-pair, AB-pair} x 11 slots.
  float2 p0a[11], p0b[11], p1a[11], p1b[11];
#pragma unroll
  for (int i = 0; i < 11; ++i) {
    p0a[i] = make_float2(0.f, 0.f); p0b[i] = p0a[i];
    p1a[i] = p0a[i]; p1b[i] = p0a[i];
  }

  float lsum = 0.f;

  // ---- prologue: stage slice c0-5 into s2[0] ----
  if (c0 - 5 >= 0) do_stage(c0 - 5, &s2[0][0][0]);
  __syncthreads();

  int p = 0;   // t mod 11 (wave-uniform)
  for (int t = 0; t < TSTEPS; ++t) {
    const int cur = t & 1, nxt = cur ^ 1;
    const int d = c0 - 5 + t;
    const bool dv = (d >= 0) && (d < DD);

    // ---- Phase A: stage(d+1)->s2[nxt] (loads issued early); W-blur(d) ----
    if ((t + 1) < TSTEPS && (d + 1) >= 0 && (d + 1) < DD)
      do_stage(d + 1, &s2[nxt][0][0]);
    if (dv) {
      const float2* sb = &s2[cur][0][0];
      wtask(sb, wr1, wg1, tb1);
      if (w2) wtask(sb, wr2, wg2, tb2);
    }
    __syncthreads();

    // ---- Phase B: H-blur + D-ring ----
    float2 B0a = make_float2(0.f, 0.f), B0b = B0a, B1a = B0a, B1b = B0a;
    if (dv) {
      const float4* tp = &t4[0][0];
#pragma unroll
      for (int u = 0; u < 12; ++u) {
        const float4 v = tp[(r0 + u) * TQ + clp2];
        const float2 vxy = make_float2(v.x, v.y);
        const float2 vzw = make_float2(v.z, v.w);
        if (u <= 10) { pk_fma(B0a, vxy, KW2[u]);     pk_fma(B0b, vzw, KW2[u]); }
        if (u >= 1)  { pk_fma(B1a, vxy, KW2[u - 1]); pk_fma(B1b, vzw, KW2[u - 1]); }
      }
    }

#define RING_CASE(P)                                                        \
    case P: {                                                               \
      if (dv) {                                                             \
        _Pragma("unroll")                                                   \
        for (int kk = 0; kk < 11; ++kk) {                                   \
          const int sl = (P + 1 + kk) % 11;                                 \
          pk_fma(p0a[sl], B0a, KW2[kk]); pk_fma(p0b[sl], B0b, KW2[kk]);     \
          pk_fma(p1a[sl], B1a, KW2[kk]); pk_fma(p1b[sl], B1b, KW2[kk]);     \
        }                                                                   \
      }                                                                     \
      const int sc = (P + 1) % 11;                                          \
      if (t >= 10) {                                                        \
        lsum += ssim_val(p0a[sc].x, p0a[sc].y, p0b[sc].x, p0b[sc].y);       \
        lsum += ssim_val(p1a[sc].x, p1a[sc].y, p1b[sc].x, p1b[sc].y);       \
      }                                                                     \
      p0a[sc] = make_float2(0.f, 0.f); p0b[sc] = make_float2(0.f, 0.f);     \
      p1a[sc] = make_float2(0.f, 0.f); p1b[sc] = make_float2(0.f, 0.f);     \
    } break;

    switch (p) {
      RING_CASE(0) RING_CASE(1) RING_CASE(2) RING_CASE(3) RING_CASE(4)
      RING_CASE(5) RING_CASE(6) RING_CASE(7) RING_CASE(8) RING_CASE(9)
      RING_CASE(10)
    }
#undef RING_CASE
    p = (p + 1 == 11) ? 0 : p + 1;

    __syncthreads();   // protects t4/s2 overwrite next step (1-wave: cheap)
  }

  // ---- wave reduction (single wave: no LDS needed) ----
  for (int off = 32; off > 0; off >>= 1) lsum += __shfl_down(lsum, off, 64);
  if (lane == 0) partials[blockIdx.x] = lsum;
}

// ---------------------------------------------------------------------------
// Final reduction: NBLK partials -> mean (deterministic, double).
// ---------------------------------------------------------------------------
__global__ __launch_bounds__(256) void ssim_reduce(
    const float* __restrict__ partials, float* __restrict__ out) {
  __shared__ double sd[256];
  double a = 0.0;
  for (int i = threadIdx.x; i < NBLK; i += 256) a += (double)partials[i];
  sd[threadIdx.x] = a;
  __syncthreads();
  for (int s = 128; s > 0; s >>= 1) {
    if ((int)threadIdx.x < s) sd[threadIdx.x] += sd[threadIdx.x + s];
    __syncthreads();
  }
  if (threadIdx.x == 0) {
    out[0] = (float)(sd[0] / (double)((size_t)NB * DD * HH * WW));
  }
}

extern "C" void kernel_launch(void* const* d_in, const int* in_sizes, int n_in,
                              void* d_out, int out_size, void* d_ws, size_t ws_size,
                              hipStream_t stream) {
  const float* img1 = (const float*)d_in[0];
  const float* img2 = (const float*)d_in[1];
  float* out = (float*)d_out;
  float* partials = (float*)d_ws;   // NBLK floats

  ssim_fused<<<NBLK, 64, 0, stream>>>(img1, img2, partials);
  ssim_reduce<<<1, 256, 0, stream>>>(partials, out);
}

// Round 17
// 384.326 us; speedup vs baseline: 3.6627x; 3.6627x over previous
//
#include <hip/hip_runtime.h>

// Problem constants
#define NB 2
#define DD 192
#define HH 192
#define WW 192
#define HWSZ (HH * WW)
#define C1F 0.0001f
#define C2F 0.0009f

// Tiling: 1-WAVE blocks (64 threads). 8(H) x 16(W) outputs, stream D.
#define TH 8
#define TW 16
#define CHUNK 32
#define TSTEPS (CHUNK + 10)          // 42
#define NCH (DD / CHUNK)             // 6
#define NTH (HH / TH)                // 24
#define NTW (WW / TW)                // 12
#define NBLK (NB * NCH * NTH * NTW)  // 3456

#define SROWS (TH + 10)              // 18 staged/W-blurred rows
#define SCOLS 26                     // staged cols (w0-5 .. w0+20)
#define SP2 28                       // s2 row stride in float2 (even -> f4 aligned)
#define TQ 19                        // t4 row stride in quads
#define NSTG (SROWS * SCOLS)         // 468 stage tasks (8 rounds of 64)
#define NWT (SROWS * (TW / 4))       // 72 W-blur tasks (64 + 8)

// Gaussian weights, WIN=11, sigma=1.5
#define KWLIST { 0.00102838f, 0.00759876f, 0.03600077f, 0.10936071f, 0.21300556f, \
                 0.26601172f, 0.21300556f, 0.10936071f, 0.03600077f, 0.00759876f, 0.00102838f }

// Packed f32 FMA (weights as VGPR broadcast pairs).
__device__ __forceinline__ void pk_fma(float2& acc, float2 a, float2 k2) {
  asm("v_pk_fma_f32 %0, %1, %2, %0" : "+v"(acc) : "v"(a), "v"(k2));
}

// SSIM from 4 packed stats: mu1, mu2, A=blur((x+y)^2), Bm=blur((x-y)^2).
__device__ __forceinline__ float ssim_val(float mu1, float mu2, float A, float Bm) {
  const float mu1sq = mu1 * mu1, mu2sq = mu2 * mu2, mu12 = mu1 * mu2;
  const float num = (2.f * mu12 + C1F) * (0.5f * (A - Bm) - 2.f * mu12 + C2F);
  const float den = (mu1sq + mu2sq + C1F) * (0.5f * (A + Bm) - mu1sq - mu2sq + C2F);
  return num * __builtin_amdgcn_rcpf(den);
}

// NOTE (R16 lesson): NO min-waves hint here. __launch_bounds__(64,3) forced
// VGPR_Count=84 and spilled the 88-reg ring to scratch -> 4.2 GB HBM traffic.
__global__ __launch_bounds__(64) void ssim_fused(
    const float* __restrict__ x, const float* __restrict__ y,
    float* __restrict__ partials) {
  const float KW[11] = KWLIST;
  float2 KW2[11];
#pragma unroll
  for (int i = 0; i < 11; ++i) KW2[i] = make_float2(KW[i], KW[i]);

  int bid = blockIdx.x;
  const int tw = bid % NTW; bid /= NTW;
  const int th = bid % NTH; bid /= NTH;
  const int c  = bid % NCH; bid /= NCH;
  const int b  = bid;
  const int h0 = th * TH, w0 = tw * TW, c0 = c * CHUNK;

  __shared__ __align__(16) float2 s2[2][SROWS][SP2];  // staged {x,y}, dbuf
  __shared__ float4 t4[SROWS][TQ];                    // W-blurred 4 fields

  const int lane = threadIdx.x;        // 0..63
  const int cl  = lane & 15;           // own W col
  const int r0  = 2 * (lane >> 4);     // own output rows r0, r0+1 (0,2,4,6)
  // t4 store-rotation inverse: pixel col c lives at (c&~3)|(((c&3)+(c>>2))&3)
  const int clp2 = (cl & ~3) | (((cl & 3) + (cl >> 2)) & 3);

  // ---- hoisted stage-task addressing: 468 scalar tasks, 8 rounds ----
  int  sIdx[8], sOff[8];
  bool sOk[8];
#pragma unroll
  for (int k = 0; k < 8; ++k) {
    const int q = lane + 64 * k;
    const bool act = (q < NSTG);
    const int row = q / SCOLS, col = q % SCOLS;
    const int gh = h0 - 5 + row, gw = w0 - 5 + col;
    sOk[k]  = act && (unsigned)gh < (unsigned)HH && (unsigned)gw < (unsigned)WW;
    sIdx[k] = row * SP2 + col;
    sOff[k] = gh * WW + gw;
  }
  // W-blur tasks: round 1 = all 64 lanes (rows 0..15), round 2 = lanes 0..7
  const int  wr1 = lane >> 2, wg1 = lane & 3;
  const bool w2  = (lane < NWT - 64);          // 8 lanes
  const int  wr2 = 16 + (lane >> 2), wg2 = lane & 3;
  const int  tb1 = wr1 * TQ + 4 * wg1;
  const int  tb2 = wr2 * TQ + 4 * wg2;

  // zero-init both s2 buffers (OOB cols stay zero all kernel)
  {
    const float2 z = make_float2(0.f, 0.f);
    float2* sb = &s2[0][0][0];
    for (int q = lane; q < 2 * SROWS * SP2; q += 64) sb[q] = z;
  }
  __syncthreads();

  const float* xb = x + (size_t)b * DD * HWSZ;
  const float* yb = y + (size_t)b * DD * HWSZ;

  auto do_stage = [&](int g, float2* s2buf) {
    const float* xs = xb + (size_t)g * HWSZ;
    const float* ys = yb + (size_t)g * HWSZ;
#pragma unroll
    for (int k = 0; k < 8; ++k)
      if (sOk[k]) s2buf[sIdx[k]] = make_float2(xs[sOff[k]], ys[sOff[k]]);
  };

  auto wtask = [&](const float2* s2buf, int wr, int wg, int tb) {
    const float4* srow4 = (const float4*)(s2buf + wr * SP2);
    float2 a0p = make_float2(0.f, 0.f), a0q = a0p, a1p = a0p, a1q = a0p,
           a2p = a0p, a2q = a0p, a3p = a0p, a3q = a0p;
#pragma unroll
    for (int u2 = 0; u2 < 7; ++u2) {
      const float4 v2 = srow4[2 * wg + u2];   // staged cols 4wg+2u2, +1
#pragma unroll
      for (int h = 0; h < 2; ++h) {
        const int    u  = 2 * u2 + h;
        const float  xx = h ? v2.z : v2.x;
        const float  yy = h ? v2.w : v2.y;
        const float2 xy = make_float2(xx, yy);
        const float  sm = xx + yy, df = xx - yy;
        const float2 sqdq = make_float2(sm * sm, df * df);
        if (u <= 10)           { pk_fma(a0p, xy, KW2[u]);     pk_fma(a0q, sqdq, KW2[u]); }
        if (u >= 1 && u <= 11) { pk_fma(a1p, xy, KW2[u - 1]); pk_fma(a1q, sqdq, KW2[u - 1]); }
        if (u >= 2 && u <= 12) { pk_fma(a2p, xy, KW2[u - 2]); pk_fma(a2q, sqdq, KW2[u - 2]); }
        if (u >= 3)            { pk_fma(a3p, xy, KW2[u - 3]); pk_fma(a3q, sqdq, KW2[u - 3]); }
      }
    }
    float4* tp = &t4[0][0];
    tp[tb + ((0 + wg) & 3)] = make_float4(a0p.x, a0p.y, a0q.x, a0q.y);
    tp[tb + ((1 + wg) & 3)] = make_float4(a1p.x, a1p.y, a1q.x, a1q.y);
    tp[tb + ((2 + wg) & 3)] = make_float4(a2p.x, a2p.y, a2q.x, a2q.y);
    tp[tb + ((3 + wg) & 3)] = make_float4(a3p.x, a3p.y, a3q.x, a3q.y);
  };

  // Ring accumulators: 2 output rows x {mu-pair, AB-pair} x 11 slots.
  float2 p0a[11], p0b[11], p1a[11], p1b[11];
#pragma unroll
  for (int i = 0; i < 11; ++i) {
    p0a[i] = make_float2(0.f, 0.f); p0b[i] = p0a[i];
    p1a[i] = p0a[i]; p1b[i] = p0a[i];
  }

  float lsum = 0.f;

  // ---- prologue: stage slice c0-5 into s2[0] ----
  if (c0 - 5 >= 0) do_stage(c0 - 5, &s2[0][0][0]);
  __syncthreads();

  int p = 0;   // t mod 11 (wave-uniform)
  for (int t = 0; t < TSTEPS; ++t) {
    const int cur = t & 1, nxt = cur ^ 1;
    const int d = c0 - 5 + t;
    const bool dv = (d >= 0) && (d < DD);

    // ---- Phase A: stage(d+1)->s2[nxt] (loads issued early); W-blur(d) ----
    if ((t + 1) < TSTEPS && (d + 1) >= 0 && (d + 1) < DD)
      do_stage(d + 1, &s2[nxt][0][0]);
    if (dv) {
      const float2* sb = &s2[cur][0][0];
      wtask(sb, wr1, wg1, tb1);
      if (w2) wtask(sb, wr2, wg2, tb2);
    }
    __syncthreads();

    // ---- Phase B: H-blur + D-ring ----
    float2 B0a = make_float2(0.f, 0.f), B0b = B0a, B1a = B0a, B1b = B0a;
    if (dv) {
      const float4* tp = &t4[0][0];
#pragma unroll
      for (int u = 0; u < 12; ++u) {
        const float4 v = tp[(r0 + u) * TQ + clp2];
        const float2 vxy = make_float2(v.x, v.y);
        const float2 vzw = make_float2(v.z, v.w);
        if (u <= 10) { pk_fma(B0a, vxy, KW2[u]);     pk_fma(B0b, vzw, KW2[u]); }
        if (u >= 1)  { pk_fma(B1a, vxy, KW2[u - 1]); pk_fma(B1b, vzw, KW2[u - 1]); }
      }
    }

#define RING_CASE(P)                                                        \
    case P: {                                                               \
      if (dv) {                                                             \
        _Pragma("unroll")                                                   \
        for (int kk = 0; kk < 11; ++kk) {                                   \
          const int sl = (P + 1 + kk) % 11;                                 \
          pk_fma(p0a[sl], B0a, KW2[kk]); pk_fma(p0b[sl], B0b, KW2[kk]);     \
          pk_fma(p1a[sl], B1a, KW2[kk]); pk_fma(p1b[sl], B1b, KW2[kk]);     \
        }                                                                   \
      }                                                                     \
      const int sc = (P + 1) % 11;                                          \
      if (t >= 10) {                                                        \
        lsum += ssim_val(p0a[sc].x, p0a[sc].y, p0b[sc].x, p0b[sc].y);       \
        lsum += ssim_val(p1a[sc].x, p1a[sc].y, p1b[sc].x, p1b[sc].y);       \
      }                                                                     \
      p0a[sc] = make_float2(0.f, 0.f); p0b[sc] = make_float2(0.f, 0.f);     \
      p1a[sc] = make_float2(0.f, 0.f); p1b[sc] = make_float2(0.f, 0.f);     \
    } break;

    switch (p) {
      RING_CASE(0) RING_CASE(1) RING_CASE(2) RING_CASE(3) RING_CASE(4)
      RING_CASE(5) RING_CASE(6) RING_CASE(7) RING_CASE(8) RING_CASE(9)
      RING_CASE(10)
    }
#undef RING_CASE
    p = (p + 1 == 11) ? 0 : p + 1;

    __syncthreads();   // protects t4/s2 overwrite next step (1-wave: cheap)
  }

  // ---- wave reduction (single wave: no LDS needed) ----
  for (int off = 32; off > 0; off >>= 1) lsum += __shfl_down(lsum, off, 64);
  if (lane == 0) partials[blockIdx.x] = lsum;
}

// ---------------------------------------------------------------------------
// Final reduction: NBLK partials -> mean (deterministic, double).
// ---------------------------------------------------------------------------
__global__ __launch_bounds__(256) void ssim_reduce(
    const float* __restrict__ partials, float* __restrict__ out) {
  __shared__ double sd[256];
  double a = 0.0;
  for (int i = threadIdx.x; i < NBLK; i += 256) a += (double)partials[i];
  sd[threadIdx.x] = a;
  __syncthreads();
  for (int s = 128; s > 0; s >>= 1) {
    if ((int)threadIdx.x < s) sd[threadIdx.x] += sd[threadIdx.x + s];
    __syncthreads();
  }
  if (threadIdx.x == 0) {
    out[0] = (float)(sd[0] / (double)((size_t)NB * DD * HH * WW));
  }
}

extern "C" void kernel_launch(void* const* d_in, const int* in_sizes, int n_in,
                              void* d_out, int out_size, void* d_ws, size_t ws_size,
                              hipStream_t stream) {
  const float* img1 = (const float*)d_in[0];
  const float* img2 = (const float*)d_in[1];
  float* out = (float*)d_out;
  float* partials = (float*)d_ws;   // NBLK floats

  ssim_fused<<<NBLK, 64, 0, stream>>>(img1, img2, partials);
  ssim_reduce<<<1, 256, 0, stream>>>(partials, out);
}

// Round 19
// 187.923 us; speedup vs baseline: 7.4907x; 2.0451x over previous
//
#include <hip/hip_runtime.h>
#include <hip/hip_fp16.h>

// Problem constants
#define NB 2
#define DD 192
#define HH 192
#define WW 192
#define HWSZ (HH * WW)
#define FELEMS ((size_t)NB * DD * HH * WW)   // 14,155,776
#define C1F 0.0001f
#define C2F 0.0009f

// Shared tile geometry (P1 and fallback): 16(H) x 32(W), 256 threads
#define TH 16
#define TW 32
#define NTH (HH / TH)                // 12
#define NTW (WW / TW)                // 6
#define NTILE (NTH * NTW)            // 72
#define SROWS (TH + 10)              // 26
#define SCOLS 42
#define SQ 43                        // s4 row stride in quads
#define TQ 36                        // t4 row stride in quads
#define NSTG (SROWS * SCOLS)         // 1092
#define NWT (SROWS * (TW / 4))       // 208

// Fallback streaming config (R9-best, benched 167 us)
#define FB_CHUNK 24
#define FB_TSTEPS (FB_CHUNK + 10)    // 34
#define FB_NCH (DD / FB_CHUNK)       // 8
#define FB_NBLK (NB * FB_NCH * NTH * NTW)  // 1152

// P2 config
#define DC 48
#define NDC (DD / DC)                // 4
#define NP2 (NB * HH * NDC)          // 1536

// Gaussian weights, WIN=11, sigma=1.5
#define KWLIST { 0.00102838f, 0.00759876f, 0.03600077f, 0.10936071f, 0.21300556f, \
                 0.26601172f, 0.21300556f, 0.10936071f, 0.03600077f, 0.00759876f, 0.00102838f }

// Packed f32 FMA (weights as VGPR broadcast pairs — proven R14/R17).
__device__ __forceinline__ void pk_fma(float2& acc, float2 a, float2 k2) {
  asm("v_pk_fma_f32 %0, %1, %2, %0" : "+v"(acc) : "v"(a), "v"(k2));
}

// SSIM from 4 packed stats: mu1, mu2, A=blur((x+y)^2), Bm=blur((x-y)^2).
__device__ __forceinline__ float ssim_val(float mu1, float mu2, float A, float Bm) {
  const float mu1sq = mu1 * mu1, mu2sq = mu2 * mu2, mu12 = mu1 * mu2;
  const float num = (2.f * mu12 + C1F) * (0.5f * (A - Bm) - 2.f * mu12 + C2F);
  const float den = (mu1sq + mu2sq + C1F) * (0.5f * (A + Bm) - mu1sq - mu2sq + C2F);
  return num * __builtin_amdgcn_rcpf(den);
}

// ===========================================================================
// Pass 1: per (b, d, tile): WH-blur of 4 fields, pack to fp16 pairs.
// 27648 fully independent blocks, 2 barriers each — no streaming chain.
// ===========================================================================
__global__ __launch_bounds__(256) void ssim_p1(
    const float* __restrict__ x, const float* __restrict__ y,
    __half2* __restrict__ pa, __half2* __restrict__ pb) {
  const float KW[11] = KWLIST;

  int bid = blockIdx.x;
  const int tile = bid % NTILE; bid /= NTILE;   // consecutive bids share slice
  const int d = bid % DD;
  const int b = bid / DD;
  const int tw = tile % NTW, th = tile / NTW;
  const int h0 = th * TH, w0 = tw * TW;

  __shared__ float4 s4[SROWS][SQ];   // staged {x, y, (x+y)^2, (x-y)^2}
  __shared__ float4 t4[SROWS][TQ];   // W-blurred (store-rotated)

  const int tid = threadIdx.x;
  const int cl = tid & 31;
  const int r0 = 2 * (tid >> 5);     // rows r0, r0+1
  const int clp2 = (cl & ~3) | (((cl & 3) + (cl >> 2)) & 3);

  const float* xs = x + (size_t)(b * DD + d) * HWSZ;
  const float* ys = y + (size_t)(b * DD + d) * HWSZ;

  // stage (zero outside image; pad col 42 never read)
  for (int q = tid; q < NSTG; q += 256) {
    const int row = q / SCOLS, col = q % SCOLS;
    const int gh = h0 - 5 + row, gw = w0 - 5 + col;
    float xx = 0.f, yy = 0.f;
    if ((unsigned)gh < (unsigned)HH && (unsigned)gw < (unsigned)WW) {
      const int o = gh * WW + gw;
      xx = xs[o]; yy = ys[o];
    }
    const float sm = xx + yy, df = xx - yy;
    s4[row][col] = make_float4(xx, yy, sm * sm, df * df);
  }
  __syncthreads();

  // W-blur: 208 tasks, 4 outputs each, rotated stores
  if (tid < NWT) {
    const int wr = tid >> 3, wq = tid & 7;
    const float4* srow = &s4[wr][0];
    float4 a0 = make_float4(0.f, 0.f, 0.f, 0.f), a1 = a0, a2 = a0, a3 = a0;
#pragma unroll
    for (int u = 0; u < 14; ++u) {
      const float4 v = srow[4 * wq + u];
      if (u <= 10)           { const float k = KW[u];     a0.x += k*v.x; a0.y += k*v.y; a0.z += k*v.z; a0.w += k*v.w; }
      if (u >= 1 && u <= 11) { const float k = KW[u - 1]; a1.x += k*v.x; a1.y += k*v.y; a1.z += k*v.z; a1.w += k*v.w; }
      if (u >= 2 && u <= 12) { const float k = KW[u - 2]; a2.x += k*v.x; a2.y += k*v.y; a2.z += k*v.z; a2.w += k*v.w; }
      if (u >= 3)            { const float k = KW[u - 3]; a3.x += k*v.x; a3.y += k*v.y; a3.z += k*v.z; a3.w += k*v.w; }
    }
    float4* tb = &t4[0][0];
    const int tBase = wr * TQ + 4 * wq;
    tb[tBase + ((0 + wq) & 3)] = a0;
    tb[tBase + ((1 + wq) & 3)] = a1;
    tb[tBase + ((2 + wq) & 3)] = a2;
    tb[tBase + ((3 + wq) & 3)] = a3;
  }
  __syncthreads();

  // H-blur: 2 rows per thread (sliding window, 12 reads), pack + store
  float4 B0 = make_float4(0.f, 0.f, 0.f, 0.f), B1 = B0;
#pragma unroll
  for (int u = 0; u < 12; ++u) {
    const float4 v = t4[r0 + u][clp2];
    if (u <= 10) { const float k = KW[u];     B0.x += k*v.x; B0.y += k*v.y; B0.z += k*v.z; B0.w += k*v.w; }
    if (u >= 1)  { const float k = KW[u - 1]; B1.x += k*v.x; B1.y += k*v.y; B1.z += k*v.z; B1.w += k*v.w; }
  }
  const size_t idx0 = ((size_t)(b * DD + d) * HH + (h0 + r0)) * WW + (w0 + cl);
  pa[idx0] = __float22half2_rn(make_float2(B0.x, B0.y));
  pb[idx0] = __float22half2_rn(make_float2(B0.z, B0.w));
  const size_t idx1 = idx0 + WW;
  pa[idx1] = __float22half2_rn(make_float2(B1.x, B1.y));
  pb[idx1] = __float22half2_rn(make_float2(B1.z, B1.w));
}

// ===========================================================================
// Pass 2: per (b, h, d-chunk): one thread per W column; D-blur via in-register
// mod-11 ring. Zero LDS in the loop, zero barriers, coalesced fp16 loads.
// ===========================================================================
__global__ __launch_bounds__(192) void ssim_p2(
    const __half2* __restrict__ pa, const __half2* __restrict__ pb,
    float* __restrict__ partials) {
  const float KW[11] = KWLIST;
  float2 KW2[11];
#pragma unroll
  for (int i = 0; i < 11; ++i) KW2[i] = make_float2(KW[i], KW[i]);

  int bid = blockIdx.x;
  const int h = bid % HH; bid /= HH;
  const int dc = bid % NDC;
  const int b = bid / NDC;
  const int w = threadIdx.x;   // 0..191

  const size_t rowoff = ((size_t)b * DD * HH + h) * WW + w;  // + d*HWSZ per d

  float2 ra[11], rb[11];
#pragma unroll
  for (int i = 0; i < 11; ++i) { ra[i] = make_float2(0.f, 0.f); rb[i] = ra[i]; }

  float lsum = 0.f;
  const int dbase = dc * DC - 5;

  __half2 va = __floats2half2_rn(0.f, 0.f), vb = va;
  if (dbase >= 0) {
    const size_t o = rowoff + (size_t)dbase * HWSZ;
    va = pa[o]; vb = pb[o];
  }

  int p = 0;
  for (int s = 0; s < DC + 10; ++s) {
    const int d = dbase + s;
    // prefetch next slice (hides L2/HBM latency under ring math)
    __half2 na = __floats2half2_rn(0.f, 0.f), nb2 = na;
    const int dn = d + 1;
    if ((s + 1) < DC + 10 && dn >= 0 && dn < DD) {
      const size_t o = rowoff + (size_t)dn * HWSZ;
      na = pa[o]; nb2 = pb[o];
    }
    const float2 fa = __half22float2(va);   // {mu1, mu2} WH-blurred
    const float2 fb = __half22float2(vb);   // {sum2, diff2} WH-blurred
    // (d invalid -> va/vb stayed zero: accumulating zero is harmless)

#define RC2(P)                                                              \
    case P: {                                                               \
      _Pragma("unroll")                                                     \
      for (int kk = 0; kk < 11; ++kk) {                                     \
        const int sl = (P + 1 + kk) % 11;                                   \
        pk_fma(ra[sl], fa, KW2[kk]);                                        \
        pk_fma(rb[sl], fb, KW2[kk]);                                        \
      }                                                                     \
      const int sc = (P + 1) % 11;                                          \
      if (s >= 10)                                                          \
        lsum += ssim_val(ra[sc].x, ra[sc].y, rb[sc].x, rb[sc].y);           \
      ra[sc] = make_float2(0.f, 0.f); rb[sc] = make_float2(0.f, 0.f);       \
    } break;

    switch (p) {
      RC2(0) RC2(1) RC2(2) RC2(3) RC2(4) RC2(5)
      RC2(6) RC2(7) RC2(8) RC2(9) RC2(10)
    }
#undef RC2
    p = (p + 1 == 11) ? 0 : p + 1;
    va = na; vb = nb2;
  }

  // block reduction: 3 waves
  for (int off = 32; off > 0; off >>= 1) lsum += __shfl_down(lsum, off, 64);
  __shared__ float wsum[3];
  if ((threadIdx.x & 63) == 0) wsum[threadIdx.x >> 6] = lsum;
  __syncthreads();
  if (threadIdx.x == 0) partials[blockIdx.x] = wsum[0] + wsum[1] + wsum[2];
}

// ===========================================================================
// Fallback: R9-best fused streaming kernel (benched 167 us, absmax 0).
// ===========================================================================
__global__ __launch_bounds__(256) void ssim_fb(
    const float* __restrict__ x, const float* __restrict__ y,
    float* __restrict__ partials) {
  const float KW[11] = KWLIST;

  int bid = blockIdx.x;
  const int tw = bid % NTW; bid /= NTW;
  const int th = bid % NTH; bid /= NTH;
  const int c  = bid % FB_NCH; bid /= FB_NCH;
  const int b  = bid;
  const int h0 = th * TH, w0 = tw * TW, c0 = c * FB_CHUNK;

  __shared__ float4 s4[SROWS][SQ];
  __shared__ float4 t4[SROWS][TQ];

  const int tid = threadIdx.x;
  const int cl  = tid & 31;
  const int r0  = 2 * (tid >> 5);
  const int clp2 = (cl & ~3) | (((cl & 3) + (cl >> 2)) & 3);

  int  sIdx[5], sOff[5];
  bool sOk[5];
#pragma unroll
  for (int k = 0; k < 5; ++k) {
    const int q = tid + 256 * k;
    const bool act = (q < NSTG);
    const int row = q / SCOLS, col = q % SCOLS;
    const int gh = h0 - 5 + row, gw = w0 - 5 + col;
    sOk[k]  = act && (unsigned)gh < (unsigned)HH && (unsigned)gw < (unsigned)WW;
    sIdx[k] = row * SQ + col;
    sOff[k] = gh * WW + gw;
  }
  const bool wAct = (tid < NWT);
  const int  wr = tid >> 3;
  const int  wq = tid & 7;
  const int  tBase = wr * TQ + 4 * wq;
  const int  st0 = tBase + ((0 + wq) & 3);
  const int  st1 = tBase + ((1 + wq) & 3);
  const int  st2 = tBase + ((2 + wq) & 3);
  const int  st3 = tBase + ((3 + wq) & 3);

  {
    const float4 z = make_float4(0.f, 0.f, 0.f, 0.f);
    for (int q = tid; q < SROWS * SQ; q += 256) (&s4[0][0])[q] = z;
  }
  __syncthreads();

  const float* xb = x + (size_t)b * DD * HWSZ;
  const float* yb = y + (size_t)b * DD * HWSZ;

  float pend0[4][11], pend1[4][11];
#pragma unroll
  for (int f = 0; f < 4; ++f)
#pragma unroll
    for (int i = 0; i < 11; ++i) { pend0[f][i] = 0.f; pend1[f][i] = 0.f; }

  float px[5], py[5];
#pragma unroll
  for (int k = 0; k < 5; ++k) { px[k] = 0.f; py[k] = 0.f; }

  if (c0 >= 5) {
    const float* xs = xb + (size_t)(c0 - 5) * HWSZ;
    const float* ys = yb + (size_t)(c0 - 5) * HWSZ;
#pragma unroll
    for (int k = 0; k < 5; ++k)
      if (sOk[k]) { px[k] = xs[sOff[k]]; py[k] = ys[sOff[k]]; }
  }

  float lsum = 0.f;
  int p = 0;

  for (int t = 0; t < FB_TSTEPS; ++t) {
    const int d = c0 - 5 + t;
    const bool dv = (d >= 0) && (d < DD);

    if (dv) {
#pragma unroll
      for (int k = 0; k < 5; ++k)
        if (sOk[k]) {
          const float xx = px[k], yy = py[k];
          const float sm = xx + yy, df = xx - yy;
          (&s4[0][0])[sIdx[k]] = make_float4(xx, yy, sm * sm, df * df);
        }
    }
    {
      const int dn = d + 1;
      if ((t + 1) < FB_TSTEPS && dn >= 0 && dn < DD) {
        const float* xs = xb + (size_t)dn * HWSZ;
        const float* ys = yb + (size_t)dn * HWSZ;
#pragma unroll
        for (int k = 0; k < 5; ++k)
          if (sOk[k]) { px[k] = xs[sOff[k]]; py[k] = ys[sOff[k]]; }
      }
    }

    float4 B0 = make_float4(0.f, 0.f, 0.f, 0.f);
    float4 B1 = B0;

    if (dv) {
      __syncthreads();
      if (wAct) {
        const float4* srow = &s4[wr][0];
        float4 a0 = make_float4(0.f, 0.f, 0.f, 0.f), a1 = a0, a2 = a0, a3 = a0;
#pragma unroll
        for (int u = 0; u < 14; ++u) {
          const float4 v = srow[4 * wq + u];
          if (u <= 10)           { const float k = KW[u];     a0.x += k*v.x; a0.y += k*v.y; a0.z += k*v.z; a0.w += k*v.w; }
          if (u >= 1 && u <= 11) { const float k = KW[u - 1]; a1.x += k*v.x; a1.y += k*v.y; a1.z += k*v.z; a1.w += k*v.w; }
          if (u >= 2 && u <= 12) { const float k = KW[u - 2]; a2.x += k*v.x; a2.y += k*v.y; a2.z += k*v.z; a2.w += k*v.w; }
          if (u >= 3)            { const float k = KW[u - 3]; a3.x += k*v.x; a3.y += k*v.y; a3.z += k*v.z; a3.w += k*v.w; }
        }
        float4* tb = &t4[0][0];
        tb[st0] = a0; tb[st1] = a1; tb[st2] = a2; tb[st3] = a3;
      }
      __syncthreads();

#pragma unroll
      for (int u = 0; u < 12; ++u) {
        const float4 v = t4[r0 + u][clp2];
        if (u <= 10) { const float k = KW[u];     B0.x += k*v.x; B0.y += k*v.y; B0.z += k*v.z; B0.w += k*v.w; }
        if (u >= 1)  { const float k = KW[u - 1]; B1.x += k*v.x; B1.y += k*v.y; B1.z += k*v.z; B1.w += k*v.w; }
      }
    }

#define RING_CASE(P)                                                        \
    case P: {                                                               \
      if (dv) {                                                             \
        _Pragma("unroll")                                                   \
        for (int kk = 0; kk < 11; ++kk) {                                   \
          const int   sl = (P + 1 + kk) % 11;                               \
          const float wg = KW[kk];                                          \
          pend0[0][sl] += wg * B0.x; pend0[1][sl] += wg * B0.y;             \
          pend0[2][sl] += wg * B0.z; pend0[3][sl] += wg * B0.w;             \
          pend1[0][sl] += wg * B1.x; pend1[1][sl] += wg * B1.y;             \
          pend1[2][sl] += wg * B1.z; pend1[3][sl] += wg * B1.w;             \
        }                                                                   \
      }                                                                     \
      const int sc = (P + 1) % 11;                                          \
      if (t >= 10) {                                                        \
        lsum += ssim_val(pend0[0][sc], pend0[1][sc], pend0[2][sc], pend0[3][sc]); \
        lsum += ssim_val(pend1[0][sc], pend1[1][sc], pend1[2][sc], pend1[3][sc]); \
      }                                                                     \
      pend0[0][sc] = 0.f; pend0[1][sc] = 0.f;                               \
      pend0[2][sc] = 0.f; pend0[3][sc] = 0.f;                               \
      pend1[0][sc] = 0.f; pend1[1][sc] = 0.f;                               \
      pend1[2][sc] = 0.f; pend1[3][sc] = 0.f;                               \
    } break;

    switch (p) {
      RING_CASE(0) RING_CASE(1) RING_CASE(2) RING_CASE(3) RING_CASE(4)
      RING_CASE(5) RING_CASE(6) RING_CASE(7) RING_CASE(8) RING_CASE(9)
      RING_CASE(10)
    }
#undef RING_CASE
    p = (p + 1 == 11) ? 0 : p + 1;
  }

  for (int off = 32; off > 0; off >>= 1) lsum += __shfl_down(lsum, off, 64);
  __shared__ float wsum[4];
  if ((tid & 63) == 0) wsum[tid >> 6] = lsum;
  __syncthreads();
  if (tid == 0) partials[blockIdx.x] = wsum[0] + wsum[1] + wsum[2] + wsum[3];
}

// ---------------------------------------------------------------------------
// Final reduction: n partials -> mean (deterministic, double).
// ---------------------------------------------------------------------------
__global__ __launch_bounds__(256) void ssim_reduce(
    const float* __restrict__ partials, int n, float* __restrict__ out) {
  __shared__ double sd[256];
  double a = 0.0;
  for (int i = threadIdx.x; i < n; i += 256) a += (double)partials[i];
  sd[threadIdx.x] = a;
  __syncthreads();
  for (int s = 128; s > 0; s >>= 1) {
    if ((int)threadIdx.x < s) sd[threadIdx.x] += sd[threadIdx.x + s];
    __syncthreads();
  }
  if (threadIdx.x == 0) out[0] = (float)(sd[0] / (double)FELEMS);
}

extern "C" void kernel_launch(void* const* d_in, const int* in_sizes, int n_in,
                              void* d_out, int out_size, void* d_ws, size_t ws_size,
                              hipStream_t stream) {
  const float* img1 = (const float*)d_in[0];
  const float* img2 = (const float*)d_in[1];
  float* out = (float*)d_out;

  const size_t need = FELEMS * 8 + (size_t)NP2 * 4 + 256;  // pa + pb + partials
  if (ws_size >= need) {
    __half2* pa = (__half2*)d_ws;
    __half2* pb = pa + FELEMS;
    float* partials = (float*)(pb + FELEMS);
    ssim_p1<<<NB * DD * NTILE, 256, 0, stream>>>(img1, img2, pa, pb);
    ssim_p2<<<NP2, 192, 0, stream>>>(pa, pb, partials);
    ssim_reduce<<<1, 256, 0, stream>>>(partials, NP2, out);
  } else {
    float* partials = (float*)d_ws;   // FB_NBLK floats
    ssim_fb<<<FB_NBLK, 256, 0, stream>>>(img1, img2, partials);
    ssim_reduce<<<1, 256, 0, stream>>>(partials, FB_NBLK, out);
  }
}

// Round 20
// 182.659 us; speedup vs baseline: 7.7065x; 1.0288x over previous
//
#include <hip/hip_runtime.h>
#include <hip/hip_fp16.h>

// Problem constants
#define NB 2
#define DD 192
#define HH 192
#define WW 192
#define HWSZ (HH * WW)
#define FELEMS ((size_t)NB * DD * HH * WW)   // 14,155,776
#define C1F 0.0001f
#define C2F 0.0009f

// Shared tile geometry (P1 and fallback): 16(H) x 32(W), 256 threads
#define TH 16
#define TW 32
#define NTH (HH / TH)                // 12
#define NTW (WW / TW)                // 6
#define NTILE (NTH * NTW)            // 72
#define SROWS (TH + 10)              // 26
#define SCOLS 42
#define SQ 43                        // fallback s4 row stride in quads
#define TQ 36                        // t4 row stride in quads
#define NSTG (SROWS * SCOLS)         // 1092 (fallback)
#define NWT (SROWS * (TW / 4))       // 208

// Fallback streaming config (R9-best, benched 167 us)
#define FB_CHUNK 24
#define FB_TSTEPS (FB_CHUNK + 10)    // 34
#define FB_NCH (DD / FB_CHUNK)       // 8
#define FB_NBLK (NB * FB_NCH * NTH * NTW)  // 1152

// P2 config
#define DC 48
#define NDC (DD / DC)                // 4
#define NP2 (NB * HH * NDC)          // 1536

// Gaussian weights, WIN=11, sigma=1.5
#define KWLIST { 0.00102838f, 0.00759876f, 0.03600077f, 0.10936071f, 0.21300556f, \
                 0.26601172f, 0.21300556f, 0.10936071f, 0.03600077f, 0.00759876f, 0.00102838f }

// Packed f32 FMA (weights as VGPR broadcast pairs — proven R14/R17).
__device__ __forceinline__ void pk_fma(float2& acc, float2 a, float2 k2) {
  asm("v_pk_fma_f32 %0, %1, %2, %0" : "+v"(acc) : "v"(a), "v"(k2));
}

// SSIM from 4 packed stats: mu1, mu2, A=blur((x+y)^2), Bm=blur((x-y)^2).
__device__ __forceinline__ float ssim_val(float mu1, float mu2, float A, float Bm) {
  const float mu1sq = mu1 * mu1, mu2sq = mu2 * mu2, mu12 = mu1 * mu2;
  const float num = (2.f * mu12 + C1F) * (0.5f * (A - Bm) - 2.f * mu12 + C2F);
  const float den = (mu1sq + mu2sq + C1F) * (0.5f * (A + Bm) - mu1sq - mu2sq + C2F);
  return num * __builtin_amdgcn_rcpf(den);
}

// ===========================================================================
// Pass 1 (R20: NO s4 staging): W-blur reads x,y DIRECTLY from global as 5
// aligned float4 per array (window [4wq-8, 4wq+11]; every load fully-in or
// fully-out since col0 % 4 == 0). Fields computed inline. LDS = t4 only
// (15 KB) -> 8 blocks/CU (thread-capped). One barrier per block.
// ===========================================================================
__global__ __launch_bounds__(256) void ssim_p1(
    const float* __restrict__ x, const float* __restrict__ y,
    __half2* __restrict__ pa, __half2* __restrict__ pb) {
  const float KW[11] = KWLIST;

  int bid = blockIdx.x;
  const int tile = bid % NTILE; bid /= NTILE;   // consecutive bids share slice
  const int d = bid % DD;
  const int b = bid / DD;
  const int tw = tile % NTW, th = tile / NTW;
  const int h0 = th * TH, w0 = tw * TW;

  __shared__ float4 t4[SROWS][TQ];   // W-blurred 4 fields (store-rotated)

  const int tid = threadIdx.x;
  const int cl = tid & 31;
  const int r0 = 2 * (tid >> 5);     // rows r0, r0+1
  const int clp2 = (cl & ~3) | (((cl & 3) + (cl >> 2)) & 3);

  const size_t slice = (size_t)(b * DD + d) * HWSZ;

  // ---- W-phase: 208 tasks, direct-from-global ----
  if (tid < NWT) {
    const int wr = tid >> 3, wq = tid & 7;
    const int gh = h0 - 5 + wr;
    const bool rowOK = (unsigned)gh < (unsigned)HH;
    const float* xr = x + slice + (size_t)gh * WW;
    const float* yr = y + slice + (size_t)gh * WW;

    // 20-value window [w0+4wq-8 .. w0+4wq+11], compile-time indexed regs
    float xs20[20], ys20[20];
#pragma unroll
    for (int j = 0; j < 5; ++j) {
      const int c0 = w0 + 4 * wq - 8 + 4 * j;   // multiple of 4
      const bool in = rowOK && (unsigned)c0 <= 188u;  // c0+3 <= 191
      float4 xv = make_float4(0.f, 0.f, 0.f, 0.f), yv = xv;
      if (in) {
        xv = *(const float4*)(xr + c0);
        yv = *(const float4*)(yr + c0);
      }
      xs20[4 * j + 0] = xv.x; xs20[4 * j + 1] = xv.y;
      xs20[4 * j + 2] = xv.z; xs20[4 * j + 3] = xv.w;
      ys20[4 * j + 0] = yv.x; ys20[4 * j + 1] = yv.y;
      ys20[4 * j + 2] = yv.z; ys20[4 * j + 3] = yv.w;
    }

    float4 a0 = make_float4(0.f, 0.f, 0.f, 0.f), a1 = a0, a2 = a0, a3 = a0;
#pragma unroll
    for (int u = 0; u < 14; ++u) {
      const float xx = xs20[u + 3];
      const float yy = ys20[u + 3];
      const float sm = xx + yy, df = xx - yy;
      const float s2q = sm * sm, d2q = df * df;
      if (u <= 10)           { const float k = KW[u];     a0.x += k*xx; a0.y += k*yy; a0.z += k*s2q; a0.w += k*d2q; }
      if (u >= 1 && u <= 11) { const float k = KW[u - 1]; a1.x += k*xx; a1.y += k*yy; a1.z += k*s2q; a1.w += k*d2q; }
      if (u >= 2 && u <= 12) { const float k = KW[u - 2]; a2.x += k*xx; a2.y += k*yy; a2.z += k*s2q; a2.w += k*d2q; }
      if (u >= 3)            { const float k = KW[u - 3]; a3.x += k*xx; a3.y += k*yy; a3.z += k*s2q; a3.w += k*d2q; }
    }
    float4* tb = &t4[0][0];
    const int tBase = wr * TQ + 4 * wq;
    tb[tBase + ((0 + wq) & 3)] = a0;
    tb[tBase + ((1 + wq) & 3)] = a1;
    tb[tBase + ((2 + wq) & 3)] = a2;
    tb[tBase + ((3 + wq) & 3)] = a3;
  }
  __syncthreads();

  // ---- H-phase: 2 rows per thread (sliding window, 12 reads), pack + store
  float4 B0 = make_float4(0.f, 0.f, 0.f, 0.f), B1 = B0;
#pragma unroll
  for (int u = 0; u < 12; ++u) {
    const float4 v = t4[r0 + u][clp2];
    if (u <= 10) { const float k = KW[u];     B0.x += k*v.x; B0.y += k*v.y; B0.z += k*v.z; B0.w += k*v.w; }
    if (u >= 1)  { const float k = KW[u - 1]; B1.x += k*v.x; B1.y += k*v.y; B1.z += k*v.z; B1.w += k*v.w; }
  }
  const size_t idx0 = (slice + (size_t)(h0 + r0) * WW) + (w0 + cl);
  pa[idx0] = __float22half2_rn(make_float2(B0.x, B0.y));
  pb[idx0] = __float22half2_rn(make_float2(B0.z, B0.w));
  const size_t idx1 = idx0 + WW;
  pa[idx1] = __float22half2_rn(make_float2(B1.x, B1.y));
  pb[idx1] = __float22half2_rn(make_float2(B1.z, B1.w));
}

// ===========================================================================
// Pass 2: per (b, h, d-chunk): one thread per W column; D-blur via in-register
// mod-11 ring. Zero LDS in the loop, zero barriers, coalesced fp16 loads.
// ===========================================================================
__global__ __launch_bounds__(192) void ssim_p2(
    const __half2* __restrict__ pa, const __half2* __restrict__ pb,
    float* __restrict__ partials) {
  const float KW[11] = KWLIST;
  float2 KW2[11];
#pragma unroll
  for (int i = 0; i < 11; ++i) KW2[i] = make_float2(KW[i], KW[i]);

  int bid = blockIdx.x;
  const int h = bid % HH; bid /= HH;
  const int dc = bid % NDC;
  const int b = bid / NDC;
  const int w = threadIdx.x;   // 0..191

  const size_t rowoff = ((size_t)b * DD * HH + h) * WW + w;  // + d*HWSZ per d

  float2 ra[11], rb[11];
#pragma unroll
  for (int i = 0; i < 11; ++i) { ra[i] = make_float2(0.f, 0.f); rb[i] = ra[i]; }

  float lsum = 0.f;
  const int dbase = dc * DC - 5;

  __half2 va = __floats2half2_rn(0.f, 0.f), vb = va;
  if (dbase >= 0) {
    const size_t o = rowoff + (size_t)dbase * HWSZ;
    va = pa[o]; vb = pb[o];
  }

  int p = 0;
  for (int s = 0; s < DC + 10; ++s) {
    const int d = dbase + s;
    // prefetch next slice (hides L2/HBM latency under ring math)
    __half2 na = __floats2half2_rn(0.f, 0.f), nb2 = na;
    const int dn = d + 1;
    if ((s + 1) < DC + 10 && dn >= 0 && dn < DD) {
      const size_t o = rowoff + (size_t)dn * HWSZ;
      na = pa[o]; nb2 = pb[o];
    }
    const float2 fa = __half22float2(va);   // {mu1, mu2} WH-blurred
    const float2 fb = __half22float2(vb);   // {sum2, diff2} WH-blurred

#define RC2(P)                                                              \
    case P: {                                                               \
      _Pragma("unroll")                                                     \
      for (int kk = 0; kk < 11; ++kk) {                                     \
        const int sl = (P + 1 + kk) % 11;                                   \
        pk_fma(ra[sl], fa, KW2[kk]);                                        \
        pk_fma(rb[sl], fb, KW2[kk]);                                        \
      }                                                                     \
      const int sc = (P + 1) % 11;                                          \
      if (s >= 10)                                                          \
        lsum += ssim_val(ra[sc].x, ra[sc].y, rb[sc].x, rb[sc].y);           \
      ra[sc] = make_float2(0.f, 0.f); rb[sc] = make_float2(0.f, 0.f);       \
    } break;

    switch (p) {
      RC2(0) RC2(1) RC2(2) RC2(3) RC2(4) RC2(5)
      RC2(6) RC2(7) RC2(8) RC2(9) RC2(10)
    }
#undef RC2
    p = (p + 1 == 11) ? 0 : p + 1;
    va = na; vb = nb2;
  }

  // block reduction: 3 waves
  for (int off = 32; off > 0; off >>= 1) lsum += __shfl_down(lsum, off, 64);
  __shared__ float wsum[3];
  if ((threadIdx.x & 63) == 0) wsum[threadIdx.x >> 6] = lsum;
  __syncthreads();
  if (threadIdx.x == 0) partials[blockIdx.x] = wsum[0] + wsum[1] + wsum[2];
}

// ===========================================================================
// Fallback: R9-best fused streaming kernel (benched 167 us, absmax 0).
// ===========================================================================
__global__ __launch_bounds__(256) void ssim_fb(
    const float* __restrict__ x, const float* __restrict__ y,
    float* __restrict__ partials) {
  const float KW[11] = KWLIST;

  int bid = blockIdx.x;
  const int tw = bid % NTW; bid /= NTW;
  const int th = bid % NTH; bid /= NTH;
  const int c  = bid % FB_NCH; bid /= FB_NCH;
  const int b  = bid;
  const int h0 = th * TH, w0 = tw * TW, c0 = c * FB_CHUNK;

  __shared__ float4 s4[SROWS][SQ];
  __shared__ float4 t4[SROWS][TQ];

  const int tid = threadIdx.x;
  const int cl  = tid & 31;
  const int r0  = 2 * (tid >> 5);
  const int clp2 = (cl & ~3) | (((cl & 3) + (cl >> 2)) & 3);

  int  sIdx[5], sOff[5];
  bool sOk[5];
#pragma unroll
  for (int k = 0; k < 5; ++k) {
    const int q = tid + 256 * k;
    const bool act = (q < NSTG);
    const int row = q / SCOLS, col = q % SCOLS;
    const int gh = h0 - 5 + row, gw = w0 - 5 + col;
    sOk[k]  = act && (unsigned)gh < (unsigned)HH && (unsigned)gw < (unsigned)WW;
    sIdx[k] = row * SQ + col;
    sOff[k] = gh * WW + gw;
  }
  const bool wAct = (tid < NWT);
  const int  wr = tid >> 3;
  const int  wq = tid & 7;
  const int  tBase = wr * TQ + 4 * wq;
  const int  st0 = tBase + ((0 + wq) & 3);
  const int  st1 = tBase + ((1 + wq) & 3);
  const int  st2 = tBase + ((2 + wq) & 3);
  const int  st3 = tBase + ((3 + wq) & 3);

  {
    const float4 z = make_float4(0.f, 0.f, 0.f, 0.f);
    for (int q = tid; q < SROWS * SQ; q += 256) (&s4[0][0])[q] = z;
  }
  __syncthreads();

  const float* xb = x + (size_t)b * DD * HWSZ;
  const float* yb = y + (size_t)b * DD * HWSZ;

  float pend0[4][11], pend1[4][11];
#pragma unroll
  for (int f = 0; f < 4; ++f)
#pragma unroll
    for (int i = 0; i < 11; ++i) { pend0[f][i] = 0.f; pend1[f][i] = 0.f; }

  float px[5], py[5];
#pragma unroll
  for (int k = 0; k < 5; ++k) { px[k] = 0.f; py[k] = 0.f; }

  if (c0 >= 5) {
    const float* xs = xb + (size_t)(c0 - 5) * HWSZ;
    const float* ys = yb + (size_t)(c0 - 5) * HWSZ;
#pragma unroll
    for (int k = 0; k < 5; ++k)
      if (sOk[k]) { px[k] = xs[sOff[k]]; py[k] = ys[sOff[k]]; }
  }

  float lsum = 0.f;
  int p = 0;

  for (int t = 0; t < FB_TSTEPS; ++t) {
    const int d = c0 - 5 + t;
    const bool dv = (d >= 0) && (d < DD);

    if (dv) {
#pragma unroll
      for (int k = 0; k < 5; ++k)
        if (sOk[k]) {
          const float xx = px[k], yy = py[k];
          const float sm = xx + yy, df = xx - yy;
          (&s4[0][0])[sIdx[k]] = make_float4(xx, yy, sm * sm, df * df);
        }
    }
    {
      const int dn = d + 1;
      if ((t + 1) < FB_TSTEPS && dn >= 0 && dn < DD) {
        const float* xs = xb + (size_t)dn * HWSZ;
        const float* ys = yb + (size_t)dn * HWSZ;
#pragma unroll
        for (int k = 0; k < 5; ++k)
          if (sOk[k]) { px[k] = xs[sOff[k]]; py[k] = ys[sOff[k]]; }
      }
    }

    float4 B0 = make_float4(0.f, 0.f, 0.f, 0.f);
    float4 B1 = B0;

    if (dv) {
      __syncthreads();
      if (wAct) {
        const float4* srow = &s4[wr][0];
        float4 a0 = make_float4(0.f, 0.f, 0.f, 0.f), a1 = a0, a2 = a0, a3 = a0;
#pragma unroll
        for (int u = 0; u < 14; ++u) {
          const float4 v = srow[4 * wq + u];
          if (u <= 10)           { const float k = KW[u];     a0.x += k*v.x; a0.y += k*v.y; a0.z += k*v.z; a0.w += k*v.w; }
          if (u >= 1 && u <= 11) { const float k = KW[u - 1]; a1.x += k*v.x; a1.y += k*v.y; a1.z += k*v.z; a1.w += k*v.w; }
          if (u >= 2 && u <= 12) { const float k = KW[u - 2]; a2.x += k*v.x; a2.y += k*v.y; a2.z += k*v.z; a2.w += k*v.w; }
          if (u >= 3)            { const float k = KW[u - 3]; a3.x += k*v.x; a3.y += k*v.y; a3.z += k*v.z; a3.w += k*v.w; }
        }
        float4* tb = &t4[0][0];
        tb[st0] = a0; tb[st1] = a1; tb[st2] = a2; tb[st3] = a3;
      }
      __syncthreads();

#pragma unroll
      for (int u = 0; u < 12; ++u) {
        const float4 v = t4[r0 + u][clp2];
        if (u <= 10) { const float k = KW[u];     B0.x += k*v.x; B0.y += k*v.y; B0.z += k*v.z; B0.w += k*v.w; }
        if (u >= 1)  { const float k = KW[u - 1]; B1.x += k*v.x; B1.y += k*v.y; B1.z += k*v.z; B1.w += k*v.w; }
      }
    }

#define RING_CASE(P)                                                        \
    case P: {                                                               \
      if (dv) {                                                             \
        _Pragma("unroll")                                                   \
        for (int kk = 0; kk < 11; ++kk) {                                   \
          const int   sl = (P + 1 + kk) % 11;                               \
          const float wg = KW[kk];                                          \
          pend0[0][sl] += wg * B0.x; pend0[1][sl] += wg * B0.y;             \
          pend0[2][sl] += wg * B0.z; pend0[3][sl] += wg * B0.w;             \
          pend1[0][sl] += wg * B1.x; pend1[1][sl] += wg * B1.y;             \
          pend1[2][sl] += wg * B1.z; pend1[3][sl] += wg * B1.w;             \
        }                                                                   \
      }                                                                     \
      const int sc = (P + 1) % 11;                                          \
      if (t >= 10) {                                                        \
        lsum += ssim_val(pend0[0][sc], pend0[1][sc], pend0[2][sc], pend0[3][sc]); \
        lsum += ssim_val(pend1[0][sc], pend1[1][sc], pend1[2][sc], pend1[3][sc]); \
      }                                                                     \
      pend0[0][sc] = 0.f; pend0[1][sc] = 0.f;                               \
      pend0[2][sc] = 0.f; pend0[3][sc] = 0.f;                               \
      pend1[0][sc] = 0.f; pend1[1][sc] = 0.f;                               \
      pend1[2][sc] = 0.f; pend1[3][sc] = 0.f;                               \
    } break;

    switch (p) {
      RING_CASE(0) RING_CASE(1) RING_CASE(2) RING_CASE(3) RING_CASE(4)
      RING_CASE(5) RING_CASE(6) RING_CASE(7) RING_CASE(8) RING_CASE(9)
      RING_CASE(10)
    }
#undef RING_CASE
    p = (p + 1 == 11) ? 0 : p + 1;
  }

  for (int off = 32; off > 0; off >>= 1) lsum += __shfl_down(lsum, off, 64);
  __shared__ float wsum[4];
  if ((tid & 63) == 0) wsum[tid >> 6] = lsum;
  __syncthreads();
  if (tid == 0) partials[blockIdx.x] = wsum[0] + wsum[1] + wsum[2] + wsum[3];
}

// ---------------------------------------------------------------------------
// Final reduction: n partials -> mean (deterministic, double).
// ---------------------------------------------------------------------------
__global__ __launch_bounds__(256) void ssim_reduce(
    const float* __restrict__ partials, int n, float* __restrict__ out) {
  __shared__ double sd[256];
  double a = 0.0;
  for (int i = threadIdx.x; i < n; i += 256) a += (double)partials[i];
  sd[threadIdx.x] = a;
  __syncthreads();
  for (int s = 128; s > 0; s >>= 1) {
    if ((int)threadIdx.x < s) sd[threadIdx.x] += sd[threadIdx.x + s];
    __syncthreads();
  }
  if (threadIdx.x == 0) out[0] = (float)(sd[0] / (double)FELEMS);
}

extern "C" void kernel_launch(void* const* d_in, const int* in_sizes, int n_in,
                              void* d_out, int out_size, void* d_ws, size_t ws_size,
                              hipStream_t stream) {
  const float* img1 = (const float*)d_in[0];
  const float* img2 = (const float*)d_in[1];
  float* out = (float*)d_out;

  const size_t need = FELEMS * 8 + (size_t)NP2 * 4 + 256;  // pa + pb + partials
  if (ws_size >= need) {
    __half2* pa = (__half2*)d_ws;
    __half2* pb = pa + FELEMS;
    float* partials = (float*)(pb + FELEMS);
    ssim_p1<<<NB * DD * NTILE, 256, 0, stream>>>(img1, img2, pa, pb);
    ssim_p2<<<NP2, 192, 0, stream>>>(pa, pb, partials);
    ssim_reduce<<<1, 256, 0, stream>>>(partials, NP2, out);
  } else {
    float* partials = (float*)d_ws;   // FB_NBLK floats
    ssim_fb<<<FB_NBLK, 256, 0, stream>>>(img1, img2, partials);
    ssim_reduce<<<1, 256, 0, stream>>>(partials, FB_NBLK, out);
  }
}